// Round 3
// baseline (70.287 us; speedup 1.0000x reference)
//
#include <hip/hip_runtime.h>
#include <hip/hip_fp16.h>
#include <math.h>

#define CRF_B 2048
#define CRF_S 4096

__device__ __forceinline__ float lse3(float x0, float x1, float x2) {
    float mx = fmaxf(fmaxf(x0, x1), x2);
    return mx + __logf(__expf(x0 - mx) + __expf(x1 - mx) + __expf(x2 - mx));
}

// ---------------------------------------------------------------------------
// One block = one batch row. 4 waves x 1024 steps.
// Phase 1: coalesced stage: em (fp16, chunk stride 50) + packed tag/mask.
// Phase 2: per-lane 16-step transfer matrix (unnormalized product form).
// Phase 3: block tree-reduction of 256 chunk matrices in log domain
//          (LDS records alias the em buffer), thread 0 writes perb[b].
// ---------------------------------------------------------------------------
__global__ __launch_bounds__(256, 5) void crf_row_kernel(
    const float* __restrict__ em,     // B*S*3
    const float* __restrict__ trans,  // 9
    const float* __restrict__ startt, // 3
    const float* __restrict__ endt,   // 3
    const int*   __restrict__ tags,   // B*S
    const int*   __restrict__ mask,   // B*S
    float* __restrict__ perb)         // B
{
    __shared__ __align__(16) unsigned char s_buf[4 * 64 * 50 * 2]; // 25600 B
    __shared__ unsigned s_tm[4][256];                              // 4096 B
    __shared__ float s_tr[9];

    __half* s_em = (__half*)s_buf;          // [4][64*50]
    float*  red  = (float*)s_buf;           // [256][13] after phase 2

    const int tid = threadIdx.x;
    const int w = tid >> 6, l = tid & 63;
    const int b = blockIdx.x;
    const long win0 = (long)b * CRF_S + (long)w * 1024;

    if (tid < 9) s_tr[tid] = trans[tid];

    // ---- stage emissions (12 float4/lane, coalesced) -> fp16 LDS ----
    const float4* g4 = (const float4*)(em + win0 * 3);
    __half* se = s_em + w * (64 * 50);
    #pragma unroll
    for (int f = 0; f < 12; ++f) {
        float4 v = g4[f * 64 + l];
        int n  = f * 64 + l;         // float4 index in window (4n = float idx)
        int ci = n / 12;             // chunk in window (48 floats/chunk)
        int r  = (n % 12) * 4;
        __half2* d = (__half2*)(se + ci * 50 + r);
        d[0] = __floats2half2_rn(v.x, v.y);
        d[1] = __floats2half2_rn(v.z, v.w);
    }
    // ---- stage tags+mask packed 1B/step ----
    const int4* t4p = (const int4*)(tags + win0);
    const int4* m4p = (const int4*)(mask + win0);
    #pragma unroll
    for (int f = 0; f < 4; ++f) {
        int4 t = t4p[f * 64 + l];
        int4 m = m4p[f * 64 + l];
        unsigned pk =  (unsigned)((t.x & 3) | ((m.x != 0) << 2))
                    | ((unsigned)((t.y & 3) | ((m.y != 0) << 2)) << 8)
                    | ((unsigned)((t.z & 3) | ((m.z != 0) << 2)) << 16)
                    | ((unsigned)((t.w & 3) | ((m.w != 0) << 2)) << 24);
        s_tm[w][f * 64 + l] = pk;
    }
    __syncthreads();

    // ---- phase 2: per-lane chunk recursion ----
    float Etr[9];
    #pragma unroll
    for (int k = 0; k < 9; ++k) Etr[k] = __expf(s_tr[k]);

    float q00=1.f,q01=0.f,q02=0.f, q10=0.f,q11=1.f,q12=0.f, q20=0.f,q21=0.f,q22=1.f;
    float C0=0.f, C1=0.f, C2=0.f;

    const __half* ce = se + l * 50;
    unsigned tmw0 = s_tm[w][l*4+0], tmw1 = s_tm[w][l*4+1],
             tmw2 = s_tm[w][l*4+2], tmw3 = s_tm[w][l*4+3];
    const unsigned char* tmb = (const unsigned char*)&s_tm[0][0]; // row-step bytes
    const int cc = tid;                                           // chunk 0..255
    int p = (cc == 0) ? (int)(tmb[0] & 3) : (int)(tmb[cc * 16 - 1] & 3);

    // thread 0 keeps step-0 data for the epilogue (red will overwrite s_em)
    float em00 = 0.f, em01 = 0.f, em02 = 0.f; int tg0 = 0, mk0 = 0;
    if (tid == 0) {
        em00 = __half2float(ce[0]); em01 = __half2float(ce[1]);
        em02 = __half2float(ce[2]);
        tg0 = tmb[0] & 3; mk0 = (tmb[0] >> 2) & 1;
    }

    float score = 0.f;
    int cnt = 0;

    #pragma unroll
    for (int t = 0; t < 16; ++t) {
        float e0 = __half2float(ce[t*3+0]);
        float e1 = __half2float(ce[t*3+1]);
        float e2 = __half2float(ce[t*3+2]);
        unsigned dw = (t < 4) ? tmw0 : (t < 8) ? tmw1 : (t < 12) ? tmw2 : tmw3;
        int byte = (int)((dw >> ((t & 3) * 8)) & 0xffu);
        int tv = byte & 3;
        int mv = byte & 4;
        bool skip = (t == 0) && (cc == 0);   // step 0 handled in epilogue
        if (mv && !skip) {
            float X0 = __expf(e0), X1 = __expf(e1), X2 = __expf(e2);
            float n0, n1, n2;
            n0 = q00*Etr[0] + q01*Etr[3] + q02*Etr[6];
            n1 = q00*Etr[1] + q01*Etr[4] + q02*Etr[7];
            n2 = q00*Etr[2] + q01*Etr[5] + q02*Etr[8];
            q00 = n0*X0; q01 = n1*X1; q02 = n2*X2;
            n0 = q10*Etr[0] + q11*Etr[3] + q12*Etr[6];
            n1 = q10*Etr[1] + q11*Etr[4] + q12*Etr[7];
            n2 = q10*Etr[2] + q11*Etr[5] + q12*Etr[8];
            q10 = n0*X0; q11 = n1*X1; q12 = n2*X2;
            n0 = q20*Etr[0] + q21*Etr[3] + q22*Etr[6];
            n1 = q20*Etr[1] + q21*Etr[4] + q22*Etr[7];
            n2 = q20*Etr[2] + q21*Etr[5] + q22*Etr[8];
            q20 = n0*X0; q21 = n1*X1; q22 = n2*X2;
            float ev = (tv == 0) ? e0 : ((tv == 1) ? e1 : e2);
            score += s_tr[p * 3 + tv] + ev;
            cnt += 1;
        }
        p = tv;
        if ((t & 3) == 3) {   // exact pow2 renorm every 4 steps
            float mx, sc; int ex;
            mx = fmaxf(fmaxf(q00, q01), q02);
            ex = ((__float_as_int(mx) >> 23) & 0xff) - 127;
            sc = __int_as_float((127 - ex) << 23);
            q00 *= sc; q01 *= sc; q02 *= sc; C0 += (float)ex * 0.6931471805599453f;
            mx = fmaxf(fmaxf(q10, q11), q12);
            ex = ((__float_as_int(mx) >> 23) & 0xff) - 127;
            sc = __int_as_float((127 - ex) << 23);
            q10 *= sc; q11 *= sc; q12 *= sc; C1 += (float)ex * 0.6931471805599453f;
            mx = fmaxf(fmaxf(q20, q21), q22);
            ex = ((__float_as_int(mx) >> 23) & 0xff) - 127;
            sc = __int_as_float((127 - ex) << 23);
            q20 *= sc; q21 *= sc; q22 *= sc; C2 += (float)ex * 0.6931471805599453f;
        }
    }

    float M[9];
    M[0] = (q00 > 0.f) ? (C0 + __logf(q00)) : -1e30f;
    M[1] = (q01 > 0.f) ? (C0 + __logf(q01)) : -1e30f;
    M[2] = (q02 > 0.f) ? (C0 + __logf(q02)) : -1e30f;
    M[3] = (q10 > 0.f) ? (C1 + __logf(q10)) : -1e30f;
    M[4] = (q11 > 0.f) ? (C1 + __logf(q11)) : -1e30f;
    M[5] = (q12 > 0.f) ? (C1 + __logf(q12)) : -1e30f;
    M[6] = (q20 > 0.f) ? (C2 + __logf(q20)) : -1e30f;
    M[7] = (q21 > 0.f) ? (C2 + __logf(q21)) : -1e30f;
    M[8] = (q22 > 0.f) ? (C2 + __logf(q22)) : -1e30f;

    // ---- phase 3: tree reduction (red aliases s_em) ----
    __syncthreads();   // all lanes done reading s_em
    {
        float* r = red + tid * 13;
        #pragma unroll
        for (int i = 0; i < 9; ++i) r[i] = M[i];
        r[9]  = score;
        r[10] = (float)cnt;
    }
    for (int st = 1; st < 256; st <<= 1) {
        __syncthreads();
        if ((tid & (2 * st - 1)) == 0) {
            float* A  = red + tid * 13;
            float* Bm = red + (tid + st) * 13;
            float N[9];
            #pragma unroll
            for (int i = 0; i < 3; ++i) {
                float a0 = A[i*3+0], a1 = A[i*3+1], a2 = A[i*3+2];
                N[i*3+0] = lse3(a0 + Bm[0], a1 + Bm[3], a2 + Bm[6]);
                N[i*3+1] = lse3(a0 + Bm[1], a1 + Bm[4], a2 + Bm[7]);
                N[i*3+2] = lse3(a0 + Bm[2], a1 + Bm[5], a2 + Bm[8]);
            }
            #pragma unroll
            for (int i = 0; i < 9; ++i) A[i] = N[i];
            A[9]  += Bm[9];
            A[10] += Bm[10];
        }
    }
    __syncthreads();

    if (tid == 0) {
        const float* A = red;
        float a0 = startt[0] + em00;
        float a1 = startt[1] + em01;
        float a2 = startt[2] + em02;
        float n0 = lse3(a0 + A[0], a1 + A[3], a2 + A[6]);
        float n1 = lse3(a0 + A[1], a1 + A[4], a2 + A[7]);
        float n2 = lse3(a0 + A[2], a1 + A[5], a2 + A[8]);
        float lp = lse3(n0 + endt[0], n1 + endt[1], n2 + endt[2]);

        float sc = A[9] + startt[tg0]
                 + ((tg0 == 0) ? em00 : (tg0 == 1) ? em01 : em02);
        int cn = (int)A[10] + mk0;
        int lastidx = (cn > 0) ? (cn - 1) : 0;
        sc += endt[tags[(long)b * CRF_S + lastidx]];

        perb[b] = lp - sc;
    }
}

// ---------------------------------------------------------------------------
// Deterministic mean over B values.
// ---------------------------------------------------------------------------
__global__ __launch_bounds__(256) void crf_reduce_kernel(
    const float* __restrict__ perb, float* __restrict__ out)
{
    __shared__ float sdata[256];
    const int tid = threadIdx.x;
    float s = 0.f;
    for (int i = tid; i < CRF_B; i += 256) s += perb[i];
    sdata[tid] = s;
    __syncthreads();
    for (int off = 128; off > 0; off >>= 1) {
        if (tid < off) sdata[tid] += sdata[tid + off];
        __syncthreads();
    }
    if (tid == 0) out[0] = sdata[0] * (1.0f / (float)CRF_B);
}

extern "C" void kernel_launch(void* const* d_in, const int* in_sizes, int n_in,
                              void* d_out, int out_size, void* d_ws, size_t ws_size,
                              hipStream_t stream)
{
    const float* em     = (const float*)d_in[0];
    const float* trans  = (const float*)d_in[1];
    const float* startt = (const float*)d_in[2];
    const float* endt   = (const float*)d_in[3];
    const int*   tags   = (const int*)d_in[4];
    const int*   mask   = (const int*)d_in[5];
    float* out = (float*)d_out;

    float* perb = (float*)d_ws;   // B floats

    crf_row_kernel<<<CRF_B, 256, 0, stream>>>(
        em, trans, startt, endt, tags, mask, perb);
    crf_reduce_kernel<<<1, 256, 0, stream>>>(perb, out);
}

// Round 4
// 49.708 us; speedup vs baseline: 1.4140x; 1.4140x over previous
//
#include <hip/hip_runtime.h>
#include <hip/hip_fp16.h>
#include <math.h>

#define CRF_B 2048
#define CRF_S 4096
#define LOG2E 1.4426950408889634f
#define LN2F  0.6931471805599453f

__device__ __forceinline__ float fexp2(float x) { return __builtin_amdgcn_exp2f(x); }

// Merge (qA,CA,scA,cnA) ∘= (qB,CB,scB,cnB): matrices in row-scaled linear form
// M[r][j] = q[r*3+j] * 2^C[r].  R = A·B done with exact pow2 scaling, no exp/log.
#define CRF_MERGE(aq0,aq1,aq2,aq3,aq4,aq5,aq6,aq7,aq8,aC0,aC1,aC2,asc,acn, \
                  bq0,bq1,bq2,bq3,bq4,bq5,bq6,bq7,bq8,bC0,bC1,bC2,bsc,bcn) { \
    int cm_ = max(max(bC0,bC1),bC2);                                        \
    int d0_=bC0-cm_, d1_=bC1-cm_, d2_=bC2-cm_;                              \
    float s0_ = (d0_>-127)? __int_as_float((127+d0_)<<23) : 0.f;            \
    float s1_ = (d1_>-127)? __int_as_float((127+d1_)<<23) : 0.f;            \
    float s2_ = (d2_>-127)? __int_as_float((127+d2_)<<23) : 0.f;            \
    float b0_=bq0*s0_, b1_=bq1*s0_, b2_=bq2*s0_;                            \
    float b3_=bq3*s1_, b4_=bq4*s1_, b5_=bq5*s1_;                            \
    float b6_=bq6*s2_, b7_=bq7*s2_, b8_=bq8*s2_;                            \
    float r0_=aq0*b0_+aq1*b3_+aq2*b6_;                                      \
    float r1_=aq0*b1_+aq1*b4_+aq2*b7_;                                      \
    float r2_=aq0*b2_+aq1*b5_+aq2*b8_;                                      \
    float r3_=aq3*b0_+aq4*b3_+aq5*b6_;                                      \
    float r4_=aq3*b1_+aq4*b4_+aq5*b7_;                                      \
    float r5_=aq3*b2_+aq4*b5_+aq5*b8_;                                      \
    float r6_=aq6*b0_+aq7*b3_+aq8*b6_;                                      \
    float r7_=aq6*b1_+aq7*b4_+aq8*b7_;                                      \
    float r8_=aq6*b2_+aq7*b5_+aq8*b8_;                                      \
    float mx_; int ex_; float sc_;                                          \
    mx_=fmaxf(fmaxf(r0_,r1_),r2_); ex_=((__float_as_int(mx_)>>23)&255)-127; \
    sc_=__int_as_float((127-ex_)<<23);                                      \
    aq0=r0_*sc_; aq1=r1_*sc_; aq2=r2_*sc_; aC0=aC0+cm_+ex_;                 \
    mx_=fmaxf(fmaxf(r3_,r4_),r5_); ex_=((__float_as_int(mx_)>>23)&255)-127; \
    sc_=__int_as_float((127-ex_)<<23);                                      \
    aq3=r3_*sc_; aq4=r4_*sc_; aq5=r5_*sc_; aC1=aC1+cm_+ex_;                 \
    mx_=fmaxf(fmaxf(r6_,r7_),r8_); ex_=((__float_as_int(mx_)>>23)&255)-127; \
    sc_=__int_as_float((127-ex_)<<23);                                      \
    aq6=r6_*sc_; aq7=r7_*sc_; aq8=r8_*sc_; aC2=aC2+cm_+ex_;                 \
    asc += bsc; acn += bcn; }

// ---------------------------------------------------------------------------
// One block = one batch row. 8 waves x 512 steps; chunk C=8 steps per lane.
// Phase 1: coalesced stage of scaled emissions (fp16) + packed tag/mask.
// Phase 2: batch chunk to registers, 8-step recursion in scaled-linear form.
// Phase 3: per-wave shfl_down reduction (no barriers, no transcendentals),
//          one barrier, thread 0 folds 8 wave-partials + epilogue.
// ---------------------------------------------------------------------------
__global__ __launch_bounds__(512, 8) void crf_row_kernel(
    const float* __restrict__ em,     // B*S*3
    const float* __restrict__ trans,  // 9
    const float* __restrict__ startt, // 3
    const float* __restrict__ endt,   // 3
    const int*   __restrict__ tags,   // B*S
    const int*   __restrict__ mask,   // B*S
    float* __restrict__ perb)         // B
{
    __shared__ __half   s_em[8 * 64 * 26];   // 26624 B; wave w: [w*1664, +1664)
    __shared__ unsigned s_tm32[1024];        // 1 byte/step: tag | mask<<2
    __shared__ float    s_ttr[9];            // trans * LOG2E (score lookup)
    __shared__ float    s_rq[8][10];         // per-wave q[9] + score
    __shared__ int      s_rc[8][4];          // per-wave C[3] + cnt

    const int tid = threadIdx.x;             // == chunk id cc (0..511)
    const int w = tid >> 6, l = tid & 63;
    const int b = blockIdx.x;
    const long win0 = (long)b * CRF_S + (long)w * 512;

    if (tid < 9) s_ttr[tid] = trans[tid] * LOG2E;

    // ---- phase 1: stage scaled emissions (6 float4/lane, coalesced) ----
    const float4* g4 = (const float4*)(em + win0 * 3);
    #pragma unroll
    for (int f = 0; f < 6; ++f) {
        float4 v = g4[f * 64 + l];
        int n  = f * 64 + l;                 // float4 index in window
        int ci = n / 6;                      // chunk in window (6 f4 per chunk)
        int r  = (n % 6) * 4;                // half offset within chunk
        __half2* d = (__half2*)(s_em + w * 1664 + ci * 26 + r);
        d[0] = __floats2half2_rn(v.x * LOG2E, v.y * LOG2E);
        d[1] = __floats2half2_rn(v.z * LOG2E, v.w * LOG2E);
    }
    // ---- stage tags+mask packed 1 B/step ----
    const int4* t4p = (const int4*)(tags + win0);
    const int4* m4p = (const int4*)(mask + win0);
    #pragma unroll
    for (int f = 0; f < 2; ++f) {
        int4 t = t4p[f * 64 + l];
        int4 m = m4p[f * 64 + l];
        unsigned pk =  (unsigned)((t.x & 3) | ((m.x != 0) << 2))
                    | ((unsigned)((t.y & 3) | ((m.y != 0) << 2)) << 8)
                    | ((unsigned)((t.z & 3) | ((m.z != 0) << 2)) << 16)
                    | ((unsigned)((t.w & 3) | ((m.w != 0) << 2)) << 24);
        s_tm32[w * 128 + f * 64 + l] = pk;
    }
    __syncthreads();

    // ---- phase 2: batch chunk to registers, then pure-VALU recursion ----
    float Etr[9];
    #pragma unroll
    for (int k = 0; k < 9; ++k) Etr[k] = __expf(trans[k]);

    const unsigned* ebase = (const unsigned*)(s_em + w * 1664 + l * 26);
    float e[24];
    #pragma unroll
    for (int k = 0; k < 12; ++k) {
        unsigned dwv = ebase[k];
        __half2 h = *(__half2*)&dwv;
        float2 f2 = __half22float2(h);
        e[2 * k] = f2.x; e[2 * k + 1] = f2.y;
    }
    const int cc = tid;
    unsigned tm0 = s_tm32[cc * 2], tm1 = s_tm32[cc * 2 + 1];
    int p = 0;
    if (cc > 0) p = (int)((s_tm32[cc * 2 - 1] >> 24) & 3u);

    float q0=1.f,q1=0.f,q2=0.f, q3=0.f,q4=1.f,q5=0.f, q6=0.f,q7=0.f,q8=1.f;
    int C0=0, C1=0, C2=0;
    float score = 0.f; int cnt = 0;

    #pragma unroll
    for (int t = 0; t < 8; ++t) {
        float e0 = e[3*t], e1 = e[3*t+1], e2 = e[3*t+2];
        unsigned dw = (t < 4) ? tm0 : tm1;
        int by = (int)((dw >> ((t & 3) * 8)) & 0xffu);
        int tv = by & 3, mv = by & 4;
        if (mv && !((t == 0) && (cc == 0))) {
            float X0 = fexp2(e0), X1 = fexp2(e1), X2 = fexp2(e2);
            float n0, n1, n2;
            n0 = q0*Etr[0] + q1*Etr[3] + q2*Etr[6];
            n1 = q0*Etr[1] + q1*Etr[4] + q2*Etr[7];
            n2 = q0*Etr[2] + q1*Etr[5] + q2*Etr[8];
            q0 = n0*X0; q1 = n1*X1; q2 = n2*X2;
            n0 = q3*Etr[0] + q4*Etr[3] + q5*Etr[6];
            n1 = q3*Etr[1] + q4*Etr[4] + q5*Etr[7];
            n2 = q3*Etr[2] + q4*Etr[5] + q5*Etr[8];
            q3 = n0*X0; q4 = n1*X1; q5 = n2*X2;
            n0 = q6*Etr[0] + q7*Etr[3] + q8*Etr[6];
            n1 = q6*Etr[1] + q7*Etr[4] + q8*Etr[7];
            n2 = q6*Etr[2] + q7*Etr[5] + q8*Etr[8];
            q6 = n0*X0; q7 = n1*X1; q8 = n2*X2;
            float ev = (tv == 0) ? e0 : (tv == 1) ? e1 : e2;
            score += s_ttr[p * 3 + tv] + ev;
            ++cnt;
        }
        p = tv;
        if ((t & 3) == 3) {   // exact pow2 renorm, integer C
            float mx; int ex; float sc;
            mx = fmaxf(fmaxf(q0, q1), q2);
            ex = ((__float_as_int(mx) >> 23) & 255) - 127;
            sc = __int_as_float((127 - ex) << 23);
            q0 *= sc; q1 *= sc; q2 *= sc; C0 += ex;
            mx = fmaxf(fmaxf(q3, q4), q5);
            ex = ((__float_as_int(mx) >> 23) & 255) - 127;
            sc = __int_as_float((127 - ex) << 23);
            q3 *= sc; q4 *= sc; q5 *= sc; C1 += ex;
            mx = fmaxf(fmaxf(q6, q7), q8);
            ex = ((__float_as_int(mx) >> 23) & 255) - 127;
            sc = __int_as_float((127 - ex) << 23);
            q6 *= sc; q7 *= sc; q8 *= sc; C2 += ex;
        }
    }

    // ---- phase 3: wave shfl_down reduction (lane i accumulates [i, i+2st)) ----
    #pragma unroll
    for (int st = 1; st < 64; st <<= 1) {
        float nq0 = __shfl_down(q0, st), nq1 = __shfl_down(q1, st),
              nq2 = __shfl_down(q2, st), nq3 = __shfl_down(q3, st),
              nq4 = __shfl_down(q4, st), nq5 = __shfl_down(q5, st),
              nq6 = __shfl_down(q6, st), nq7 = __shfl_down(q7, st),
              nq8 = __shfl_down(q8, st);
        int nC0 = __shfl_down(C0, st), nC1 = __shfl_down(C1, st),
            nC2 = __shfl_down(C2, st);
        float nsc = __shfl_down(score, st);
        int   ncn = __shfl_down(cnt, st);
        CRF_MERGE(q0,q1,q2,q3,q4,q5,q6,q7,q8,C0,C1,C2,score,cnt,
                  nq0,nq1,nq2,nq3,nq4,nq5,nq6,nq7,nq8,nC0,nC1,nC2,nsc,ncn);
    }

    if (l == 0) {
        s_rq[w][0]=q0; s_rq[w][1]=q1; s_rq[w][2]=q2;
        s_rq[w][3]=q3; s_rq[w][4]=q4; s_rq[w][5]=q5;
        s_rq[w][6]=q6; s_rq[w][7]=q7; s_rq[w][8]=q8;
        s_rq[w][9]=score;
        s_rc[w][0]=C0; s_rc[w][1]=C1; s_rc[w][2]=C2; s_rc[w][3]=cnt;
    }
    __syncthreads();

    if (tid == 0) {
        float a0=s_rq[0][0], a1=s_rq[0][1], a2=s_rq[0][2],
              a3=s_rq[0][3], a4=s_rq[0][4], a5=s_rq[0][5],
              a6=s_rq[0][6], a7=s_rq[0][7], a8=s_rq[0][8];
        float asc = s_rq[0][9];
        int AC0=s_rc[0][0], AC1=s_rc[0][1], AC2=s_rc[0][2], acn=s_rc[0][3];
        #pragma unroll
        for (int w2 = 1; w2 < 8; ++w2) {
            float m0=s_rq[w2][0], m1=s_rq[w2][1], m2=s_rq[w2][2],
                  m3=s_rq[w2][3], m4=s_rq[w2][4], m5=s_rq[w2][5],
                  m6=s_rq[w2][6], m7=s_rq[w2][7], m8=s_rq[w2][8];
            float msc = s_rq[w2][9];
            int mc0=s_rc[w2][0], mc1=s_rc[w2][1], mc2=s_rc[w2][2], mcn=s_rc[w2][3];
            CRF_MERGE(a0,a1,a2,a3,a4,a5,a6,a7,a8,AC0,AC1,AC2,asc,acn,
                      m0,m1,m2,m3,m4,m5,m6,m7,m8,mc0,mc1,mc2,msc,mcn);
        }
        // epilogue (log2 domain; s_em holds scaled emissions)
        float et0 = __half2float(s_em[0]);
        float et1 = __half2float(s_em[1]);
        float et2 = __half2float(s_em[2]);
        int by0 = (int)(s_tm32[0] & 0xffu);
        int tg0 = by0 & 3, mk0 = (by0 >> 2) & 1;

        float la0 = startt[0] * LOG2E + et0;
        float la1 = startt[1] * LOG2E + et1;
        float la2 = startt[2] * LOG2E + et2;
        float am = fmaxf(fmaxf(la0, la1), la2);
        int cm = max(max(AC0, AC1), AC2);
        float w0 = fexp2((la0 - am) + (float)(AC0 - cm));
        float w1 = fexp2((la1 - am) + (float)(AC1 - cm));
        float w2v = fexp2((la2 - am) + (float)(AC2 - cm));
        float v0 = w0*a0 + w1*a3 + w2v*a6;
        float v1 = w0*a1 + w1*a4 + w2v*a7;
        float v2 = w0*a2 + w1*a5 + w2v*a8;
        float sum = v0 * fexp2(endt[0] * LOG2E)
                  + v1 * fexp2(endt[1] * LOG2E)
                  + v2 * fexp2(endt[2] * LOG2E);
        float lp2 = am + (float)cm + __log2f(sum);

        float sc2 = asc + startt[tg0] * LOG2E
                  + ((tg0 == 0) ? et0 : (tg0 == 1) ? et1 : et2);
        int cn = acn + mk0;
        int lastidx = (cn > 0) ? (cn - 1) : 0;
        sc2 += endt[tags[(long)b * CRF_S + lastidx]] * LOG2E;

        perb[b] = LN2F * (lp2 - sc2);
    }
}

// ---------------------------------------------------------------------------
// Deterministic mean over B values.
// ---------------------------------------------------------------------------
__global__ __launch_bounds__(256) void crf_reduce_kernel(
    const float* __restrict__ perb, float* __restrict__ out)
{
    __shared__ float sdata[256];
    const int tid = threadIdx.x;
    float s = 0.f;
    for (int i = tid; i < CRF_B; i += 256) s += perb[i];
    sdata[tid] = s;
    __syncthreads();
    for (int off = 128; off > 0; off >>= 1) {
        if (tid < off) sdata[tid] += sdata[tid + off];
        __syncthreads();
    }
    if (tid == 0) out[0] = sdata[0] * (1.0f / (float)CRF_B);
}

extern "C" void kernel_launch(void* const* d_in, const int* in_sizes, int n_in,
                              void* d_out, int out_size, void* d_ws, size_t ws_size,
                              hipStream_t stream)
{
    const float* em     = (const float*)d_in[0];
    const float* trans  = (const float*)d_in[1];
    const float* startt = (const float*)d_in[2];
    const float* endt   = (const float*)d_in[3];
    const int*   tags   = (const int*)d_in[4];
    const int*   mask   = (const int*)d_in[5];
    float* out = (float*)d_out;

    float* perb = (float*)d_ws;   // B floats

    crf_row_kernel<<<CRF_B, 512, 0, stream>>>(
        em, trans, startt, endt, tags, mask, perb);
    crf_reduce_kernel<<<1, 256, 0, stream>>>(perb, out);
}

// Round 5
// 45.103 us; speedup vs baseline: 1.5584x; 1.1021x over previous
//
#include <hip/hip_runtime.h>
#include <math.h>

#define CRF_B 2048
#define CRF_S 4096
#define LN2F  0.6931471805599453f

__device__ __forceinline__ float fexp2(float x) { return __builtin_amdgcn_exp2f(x); }

// Merge (A q/C/score/cnt) ∘= (B ...): 3x3 matrices in row-scaled linear form
// M[r][j] = q[r*3+j] * 2^C[r]. R = A·B with exact pow2 scaling, no exp/log.
#define CRF_MERGE(aq0,aq1,aq2,aq3,aq4,aq5,aq6,aq7,aq8,aC0,aC1,aC2,asc,acn, \
                  bq0,bq1,bq2,bq3,bq4,bq5,bq6,bq7,bq8,bC0,bC1,bC2,bsc,bcn) { \
    int cm_ = max(max(bC0,bC1),bC2);                                        \
    int d0_=bC0-cm_, d1_=bC1-cm_, d2_=bC2-cm_;                              \
    float s0_ = (d0_>-127)? __int_as_float((127+d0_)<<23) : 0.f;            \
    float s1_ = (d1_>-127)? __int_as_float((127+d1_)<<23) : 0.f;            \
    float s2_ = (d2_>-127)? __int_as_float((127+d2_)<<23) : 0.f;            \
    float b0_=bq0*s0_, b1_=bq1*s0_, b2_=bq2*s0_;                            \
    float b3_=bq3*s1_, b4_=bq4*s1_, b5_=bq5*s1_;                            \
    float b6_=bq6*s2_, b7_=bq7*s2_, b8_=bq8*s2_;                            \
    float r0_=aq0*b0_+aq1*b3_+aq2*b6_;                                      \
    float r1_=aq0*b1_+aq1*b4_+aq2*b7_;                                      \
    float r2_=aq0*b2_+aq1*b5_+aq2*b8_;                                      \
    float r3_=aq3*b0_+aq4*b3_+aq5*b6_;                                      \
    float r4_=aq3*b1_+aq4*b4_+aq5*b7_;                                      \
    float r5_=aq3*b2_+aq4*b5_+aq5*b8_;                                      \
    float r6_=aq6*b0_+aq7*b3_+aq8*b6_;                                      \
    float r7_=aq6*b1_+aq7*b4_+aq8*b7_;                                      \
    float r8_=aq6*b2_+aq7*b5_+aq8*b8_;                                      \
    float mx_; int ex_; float sc_;                                          \
    mx_=fmaxf(fmaxf(r0_,r1_),r2_); ex_=((__float_as_int(mx_)>>23)&255)-127; \
    sc_=__int_as_float((127-ex_)<<23);                                      \
    aq0=r0_*sc_; aq1=r1_*sc_; aq2=r2_*sc_; aC0=aC0+cm_+ex_;                 \
    mx_=fmaxf(fmaxf(r3_,r4_),r5_); ex_=((__float_as_int(mx_)>>23)&255)-127; \
    sc_=__int_as_float((127-ex_)<<23);                                      \
    aq3=r3_*sc_; aq4=r4_*sc_; aq5=r5_*sc_; aC1=aC1+cm_+ex_;                 \
    mx_=fmaxf(fmaxf(r6_,r7_),r8_); ex_=((__float_as_int(mx_)>>23)&255)-127; \
    sc_=__int_as_float((127-ex_)<<23);                                      \
    aq6=r6_*sc_; aq7=r7_*sc_; aq8=r8_*sc_; aC2=aC2+cm_+ex_;                 \
    asc += bsc; acn += bcn; }

// ---------------------------------------------------------------------------
// One block = one batch row. 512 threads; lane owns an 8-step chunk loaded
// DIRECTLY from global into registers (96 B em + 32 B tags/mask per lane; a
// wave's 6 em loads share one 6 KB window -> L1 absorbs the 5 re-touches).
// Then pure-VALU 8-step recursion in row-scaled linear form, per-wave
// shfl_down log-semiring reduction, one barrier, thread 0 epilogue.
// ---------------------------------------------------------------------------
__global__ __launch_bounds__(512, 6) void crf_row_kernel(
    const float* __restrict__ em,     // B*S*3
    const float* __restrict__ trans,  // 9
    const float* __restrict__ startt, // 3
    const float* __restrict__ endt,   // 3
    const int*   __restrict__ tags,   // B*S
    const int*   __restrict__ mask,   // B*S
    float* __restrict__ perb)         // B
{
    __shared__ float s_tr[9];         // natural-log transitions (score lookup)
    __shared__ float s_rq[8][10];     // per-wave q[9] + score
    __shared__ int   s_rc[8][4];      // per-wave C[3] + cnt

    const int tid = threadIdx.x;      // chunk id within row (0..511)
    const int w = tid >> 6, l = tid & 63;
    const int b = blockIdx.x;
    const long cbase = (long)b * CRF_S + (long)tid * 8;   // chunk's first step

    if (tid < 9) s_tr[tid] = trans[tid];
    __syncthreads();

    // ---- direct global -> register loads (all independent, issued early) ----
    const float4* e4 = (const float4*)(em + cbase * 3);   // 96 B, 16B-aligned
    float4 ev0 = e4[0], ev1 = e4[1], ev2 = e4[2],
           ev3 = e4[3], ev4 = e4[4], ev5 = e4[5];
    const int4* t4 = (const int4*)(tags + cbase);
    int4 ta = t4[0], tb = t4[1];
    const int4* m4 = (const int4*)(mask + cbase);
    int4 ma = m4[0], mb = m4[1];
    int p = 0;
    if (tid > 0) p = tags[cbase - 1];     // lines cached by neighbor lanes

    float e[24] = { ev0.x, ev0.y, ev0.z, ev0.w, ev1.x, ev1.y, ev1.z, ev1.w,
                    ev2.x, ev2.y, ev2.z, ev2.w, ev3.x, ev3.y, ev3.z, ev3.w,
                    ev4.x, ev4.y, ev4.z, ev4.w, ev5.x, ev5.y, ev5.z, ev5.w };
    // pack tags (2b each) and mask (1b each) into scalars
    unsigned ttag =  (unsigned)(ta.x & 3)        | ((unsigned)(ta.y & 3) << 2)
                  | ((unsigned)(ta.z & 3) << 4)  | ((unsigned)(ta.w & 3) << 6)
                  | ((unsigned)(tb.x & 3) << 8)  | ((unsigned)(tb.y & 3) << 10)
                  | ((unsigned)(tb.z & 3) << 12) | ((unsigned)(tb.w & 3) << 14);
    unsigned tmsk =  (unsigned)(ma.x != 0)       | ((unsigned)(ma.y != 0) << 1)
                  | ((unsigned)(ma.z != 0) << 2) | ((unsigned)(ma.w != 0) << 3)
                  | ((unsigned)(mb.x != 0) << 4) | ((unsigned)(mb.y != 0) << 5)
                  | ((unsigned)(mb.z != 0) << 6) | ((unsigned)(mb.w != 0) << 7);

    float Etr[9];
    #pragma unroll
    for (int k = 0; k < 9; ++k) Etr[k] = __expf(s_tr[k]);

    float q0=1.f,q1=0.f,q2=0.f, q3=0.f,q4=1.f,q5=0.f, q6=0.f,q7=0.f,q8=1.f;
    int C0=0, C1=0, C2=0;
    float score = 0.f; int cnt = 0;

    #pragma unroll
    for (int t = 0; t < 8; ++t) {
        float e0 = e[3*t], e1 = e[3*t+1], e2 = e[3*t+2];
        int tv = (int)((ttag >> (2*t)) & 3u);
        int mv = (int)((tmsk >> t) & 1u);
        if (mv && !((t == 0) && (tid == 0))) {   // step 0 handled in epilogue
            float X0 = __expf(e0), X1 = __expf(e1), X2 = __expf(e2);
            float n0, n1, n2;
            n0 = q0*Etr[0] + q1*Etr[3] + q2*Etr[6];
            n1 = q0*Etr[1] + q1*Etr[4] + q2*Etr[7];
            n2 = q0*Etr[2] + q1*Etr[5] + q2*Etr[8];
            q0 = n0*X0; q1 = n1*X1; q2 = n2*X2;
            n0 = q3*Etr[0] + q4*Etr[3] + q5*Etr[6];
            n1 = q3*Etr[1] + q4*Etr[4] + q5*Etr[7];
            n2 = q3*Etr[2] + q4*Etr[5] + q5*Etr[8];
            q3 = n0*X0; q4 = n1*X1; q5 = n2*X2;
            n0 = q6*Etr[0] + q7*Etr[3] + q8*Etr[6];
            n1 = q6*Etr[1] + q7*Etr[4] + q8*Etr[7];
            n2 = q6*Etr[2] + q7*Etr[5] + q8*Etr[8];
            q6 = n0*X0; q7 = n1*X1; q8 = n2*X2;
            float ev = (tv == 0) ? e0 : (tv == 1) ? e1 : e2;
            score += s_tr[p * 3 + tv] + ev;      // independent ds_reads
            ++cnt;
        }
        p = tv;
        if ((t & 3) == 3) {   // exact pow2 renorm, integer exponent C
            float mx; int ex; float sc;
            mx = fmaxf(fmaxf(q0, q1), q2);
            ex = ((__float_as_int(mx) >> 23) & 255) - 127;
            sc = __int_as_float((127 - ex) << 23);
            q0 *= sc; q1 *= sc; q2 *= sc; C0 += ex;
            mx = fmaxf(fmaxf(q3, q4), q5);
            ex = ((__float_as_int(mx) >> 23) & 255) - 127;
            sc = __int_as_float((127 - ex) << 23);
            q3 *= sc; q4 *= sc; q5 *= sc; C1 += ex;
            mx = fmaxf(fmaxf(q6, q7), q8);
            ex = ((__float_as_int(mx) >> 23) & 255) - 127;
            sc = __int_as_float((127 - ex) << 23);
            q6 *= sc; q7 *= sc; q8 *= sc; C2 += ex;
        }
    }

    // ---- per-wave shfl_down log-semiring reduction (lane 0 = wave result) ----
    #pragma unroll
    for (int st = 1; st < 64; st <<= 1) {
        float nq0 = __shfl_down(q0, st), nq1 = __shfl_down(q1, st),
              nq2 = __shfl_down(q2, st), nq3 = __shfl_down(q3, st),
              nq4 = __shfl_down(q4, st), nq5 = __shfl_down(q5, st),
              nq6 = __shfl_down(q6, st), nq7 = __shfl_down(q7, st),
              nq8 = __shfl_down(q8, st);
        int nC0 = __shfl_down(C0, st), nC1 = __shfl_down(C1, st),
            nC2 = __shfl_down(C2, st);
        float nsc = __shfl_down(score, st);
        int   ncn = __shfl_down(cnt, st);
        CRF_MERGE(q0,q1,q2,q3,q4,q5,q6,q7,q8,C0,C1,C2,score,cnt,
                  nq0,nq1,nq2,nq3,nq4,nq5,nq6,nq7,nq8,nC0,nC1,nC2,nsc,ncn);
    }

    if (l == 0) {
        s_rq[w][0]=q0; s_rq[w][1]=q1; s_rq[w][2]=q2;
        s_rq[w][3]=q3; s_rq[w][4]=q4; s_rq[w][5]=q5;
        s_rq[w][6]=q6; s_rq[w][7]=q7; s_rq[w][8]=q8;
        s_rq[w][9]=score;
        s_rc[w][0]=C0; s_rc[w][1]=C1; s_rc[w][2]=C2; s_rc[w][3]=cnt;
    }
    __syncthreads();

    if (tid == 0) {
        float a0=s_rq[0][0], a1=s_rq[0][1], a2=s_rq[0][2],
              a3=s_rq[0][3], a4=s_rq[0][4], a5=s_rq[0][5],
              a6=s_rq[0][6], a7=s_rq[0][7], a8=s_rq[0][8];
        float asc = s_rq[0][9];
        int AC0=s_rc[0][0], AC1=s_rc[0][1], AC2=s_rc[0][2], acn=s_rc[0][3];
        #pragma unroll
        for (int w2 = 1; w2 < 8; ++w2) {
            float m0=s_rq[w2][0], m1=s_rq[w2][1], m2=s_rq[w2][2],
                  m3=s_rq[w2][3], m4=s_rq[w2][4], m5=s_rq[w2][5],
                  m6=s_rq[w2][6], m7=s_rq[w2][7], m8=s_rq[w2][8];
            float msc = s_rq[w2][9];
            int mc0=s_rc[w2][0], mc1=s_rc[w2][1], mc2=s_rc[w2][2], mcn=s_rc[w2][3];
            CRF_MERGE(a0,a1,a2,a3,a4,a5,a6,a7,a8,AC0,AC1,AC2,asc,acn,
                      m0,m1,m2,m3,m4,m5,m6,m7,m8,mc0,mc1,mc2,msc,mcn);
        }
        // ---- epilogue (natural log; tid 0 still holds e[0..2], tag0, mask0) ----
        int tg0 = (int)(ttag & 3u), mk0 = (int)(tmsk & 1u);
        float la0 = startt[0] + e[0];
        float la1 = startt[1] + e[1];
        float la2 = startt[2] + e[2];
        float am = fmaxf(fmaxf(la0, la1), la2);
        int cm = max(max(AC0, AC1), AC2);
        float w0 = __expf(la0 - am) * fexp2((float)(AC0 - cm));
        float w1 = __expf(la1 - am) * fexp2((float)(AC1 - cm));
        float w2v = __expf(la2 - am) * fexp2((float)(AC2 - cm));
        float v0 = w0*a0 + w1*a3 + w2v*a6;
        float v1 = w0*a1 + w1*a4 + w2v*a7;
        float v2 = w0*a2 + w1*a5 + w2v*a8;
        float sum = v0 * __expf(endt[0]) + v1 * __expf(endt[1])
                  + v2 * __expf(endt[2]);
        float lp = am + (float)cm * LN2F + __logf(sum);

        float sc = asc + startt[tg0]
                 + ((tg0 == 0) ? e[0] : (tg0 == 1) ? e[1] : e[2]);
        int cn = acn + mk0;
        int lastidx = (cn > 0) ? (cn - 1) : 0;
        sc += endt[tags[(long)b * CRF_S + lastidx]];

        perb[b] = lp - sc;
    }
}

// ---------------------------------------------------------------------------
// Deterministic mean over B values.
// ---------------------------------------------------------------------------
__global__ __launch_bounds__(256) void crf_reduce_kernel(
    const float* __restrict__ perb, float* __restrict__ out)
{
    __shared__ float sdata[256];
    const int tid = threadIdx.x;
    float s = 0.f;
    for (int i = tid; i < CRF_B; i += 256) s += perb[i];
    sdata[tid] = s;
    __syncthreads();
    for (int off = 128; off > 0; off >>= 1) {
        if (tid < off) sdata[tid] += sdata[tid + off];
        __syncthreads();
    }
    if (tid == 0) out[0] = sdata[0] * (1.0f / (float)CRF_B);
}

extern "C" void kernel_launch(void* const* d_in, const int* in_sizes, int n_in,
                              void* d_out, int out_size, void* d_ws, size_t ws_size,
                              hipStream_t stream)
{
    const float* em     = (const float*)d_in[0];
    const float* trans  = (const float*)d_in[1];
    const float* startt = (const float*)d_in[2];
    const float* endt   = (const float*)d_in[3];
    const int*   tags   = (const int*)d_in[4];
    const int*   mask   = (const int*)d_in[5];
    float* out = (float*)d_out;

    float* perb = (float*)d_ws;   // B floats

    crf_row_kernel<<<CRF_B, 512, 0, stream>>>(
        em, trans, startt, endt, tags, mask, perb);
    crf_reduce_kernel<<<1, 256, 0, stream>>>(perb, out);
}